// Round 13
// baseline (698.900 us; speedup 1.0000x reference)
//
#include <hip/hip_runtime.h>
#include <hip/hip_bf16.h>

#define NNODES 100000
#define NEDGES 1600000
#define NRELS 16
#define NBASES 8
#define DFEAT 128
#define NCLS 40
#define MAXDEG 48
#define KTOT 1152   // WT K extent: NBASES*128 + 128 (root)
#define KA   1024   // A K extent: NBASES*128 (root staged from hin)
#define NBUCK 196   // ceil(100000/512) destination buckets
#define NPAD  (NBUCK * 512)
#define BCAP  9216
#define BINBLKS 28125
#define W3BLKS  1440   // 320*1152/256

typedef __attribute__((ext_vector_type(8))) short bf16x8v;
typedef __attribute__((ext_vector_type(4))) float f32x4v;
typedef __attribute__((ext_vector_type(2))) float f32x2v;
typedef __attribute__((ext_vector_type(4))) unsigned short u16x4;
typedef unsigned long long u64;

struct __align__(8) bf16x4s { __hip_bfloat162 lo, hi; };

// ---- k_bin: cvq + edge binning + merged weight prep (R10 known-good) ----
__global__ __launch_bounds__(256)
void k_bin(const float* __restrict__ x, __hip_bfloat16* __restrict__ xb,
           short* __restrict__ q8, float* __restrict__ qs,
           const int* __restrict__ esrc, const int* __restrict__ edst,
           const int* __restrict__ etyp,
           unsigned* __restrict__ binCnt, u64* __restrict__ bins,
           const float* __restrict__ wb0, const float* __restrict__ wr0,
           const float* __restrict__ wb1, const float* __restrict__ wr1,
           const float* __restrict__ wb2, const float* __restrict__ wr2,
           __hip_bfloat16* __restrict__ WT3)
{
    unsigned bid = blockIdx.x;
    if (bid >= (unsigned)BINBLKS) {             // w3 block
        int idx = (int)(bid - BINBLKS) * 256 + threadIdx.x;
        int r = idx / KTOT, k = idx - r * KTOT;
        const float* bs; const float* rt; int o; int dout;
        if (r < 128)      { bs = wb0; rt = wr0; o = r;       dout = 128; }
        else if (r < 256) { bs = wb1; rt = wr1; o = r - 128; dout = 128; }
        else              { bs = wb2; rt = wr2; o = r - 256; dout = NCLS; }
        float v = 0.f;
        if (o < dout) v = (k < KA) ? bs[(size_t)k * dout + o]
                                   : rt[(size_t)(k - KA) * dout + o];
        WT3[idx] = __float2bfloat16(v);
        return;
    }
    if (bid % 9u == 0u) {                       // bin block: 512 edges
        __shared__ unsigned histS[NBUCK], rankS[NBUCK];
        __shared__ unsigned baseLS[NBUCK], baseGS[NBUCK];
        __shared__ unsigned wsumS[4];
        __shared__ u64 recS[512];
        int k = (int)(bid / 9u);
        int t = threadIdx.x, lane = t & 63, wv = t >> 6;
        for (int i = t; i < NBUCK; i += 256) { histS[i] = 0u; rankS[i] = 0u; }
        __syncthreads();
        int2 s2 = ((const int2*)esrc)[k * 256 + t];
        int2 d2 = ((const int2*)edst)[k * 256 + t];
        int2 t2 = ((const int2*)etyp)[k * 256 + t];
        unsigned b0 = (unsigned)d2.x >> 9, b1 = (unsigned)d2.y >> 9;
        u64 r0 = ((u64)(unsigned)d2.x << 21) | ((unsigned)s2.x << 4) | (unsigned)t2.x;
        u64 r1 = ((u64)(unsigned)d2.y << 21) | ((unsigned)s2.y << 4) | (unsigned)t2.y;
        atomicAdd(&histS[b0], 1u);
        atomicAdd(&histS[b1], 1u);
        __syncthreads();
        unsigned h = (t < NBUCK) ? histS[t] : 0u, v = h;
#pragma unroll
        for (int o = 1; o < 64; o <<= 1) {      // inclusive wave scan
            unsigned u = __shfl_up(v, o);
            if (lane >= o) v += u;
        }
        if (lane == 63) wsumS[wv] = v;
        __syncthreads();
        unsigned wo = 0;
        for (int w = 0; w < wv; w++) wo += wsumS[w];
        v += wo;
        if (t < NBUCK) {
            baseLS[t] = v - h;                  // exclusive local base
            baseGS[t] = atomicAdd(&binCnt[t], h);
        }
        __syncthreads();
        unsigned q0 = atomicAdd(&rankS[b0], 1u);
        recS[baseLS[b0] + q0] = r0;
        unsigned q1 = atomicAdd(&rankS[b1], 1u);
        recS[baseLS[b1] + q1] = r1;
        __syncthreads();
#pragma unroll
        for (int j = 0; j < 2; j++) {           // coalesced run writeout
            int idx = t + 256 * j;
            u64 rr = recS[idx];
            unsigned bb = (unsigned)(rr >> 21) >> 9;
            unsigned go = baseGS[bb] + ((unsigned)idx - baseLS[bb]);
            if (go < BCAP) bins[(size_t)bb * BCAP + go] = rr;
        }
    } else {                                    // cvq block: 4 nodes
        int cb = (int)(bid - bid / 9u - 1u);
        int wave = threadIdx.x >> 6, lane = threadIdx.x & 63;
        int v = cb * 4 + wave;
        if (v >= NNODES) return;
        float2 xv = ((const float2*)x)[(size_t)v * 64 + lane];
        __hip_bfloat162 bv;
        bv.x = __float2bfloat16(xv.x);
        bv.y = __float2bfloat16(xv.y);
        ((__hip_bfloat162*)xb)[(size_t)v * 64 + lane] = bv;
        float m = fmaxf(fabsf(xv.x), fabsf(xv.y));
#pragma unroll
        for (int o = 32; o; o >>= 1) m = fmaxf(m, __shfl_xor(m, o));
        float inv = (m > 0.f) ? 127.f / m : 0.f;
        int qx = (int)rintf(xv.x * inv), qy = (int)rintf(xv.y * inv);
        q8[(size_t)v * 64 + lane] = (short)((qx & 0xff) | (qy << 8));
        if (lane == 0) qs[v] = m * (1.f / 127.f);
    }
}

// ---- k_ell: bucket -> ELL window (MAXDEG=48) in LDS (R10 known-good) ----
__global__ __launch_bounds__(256)
void k_ell(const u64* __restrict__ bins, const unsigned* __restrict__ binCnt,
           unsigned* __restrict__ ell, unsigned* __restrict__ degD)
{
    __shared__ unsigned cntS[512];
    __shared__ unsigned ellS[512 * MAXDEG];     // 96 KB
    int b = blockIdx.x, t = threadIdx.x;
    for (int i = t; i < 512; i += 256) cntS[i] = 0u;
    __syncthreads();
    unsigned n = binCnt[b]; if (n > BCAP) n = BCAP;
    const u64* rp = bins + (size_t)b * BCAP;
    for (unsigned i = t; i < n; i += 256) {
        u64 r = rp[i];
        unsigned ld = ((unsigned)(r >> 21)) & 511u;
        unsigned slot = atomicAdd(&cntS[ld], 1u);
        if (slot < MAXDEG) ellS[ld * MAXDEG + slot] = (unsigned)(r & 0x1FFFFFu);
    }
    __syncthreads();
    size_t row0 = (size_t)b << 9;
    uint4* eo = (uint4*)(ell + row0 * MAXDEG);
    const uint4* ei = (const uint4*)ellS;
    for (int i = t; i < 512 * (MAXDEG / 4); i += 256)
        eo[i] = ei[i];                           // fully coalesced
    if (t < 256) { degD[row0 + t] = cntS[t]; degD[row0 + 256 + t] = cntS[256 + t]; }
}

// ---- k_agg: TWO nodes/wave, gather pipeline. Tail-aware batching —
// full 16-edge batches + one 8-wide tail path. Processed slots drop from
// ceil(ne/16)*16 (E~22.8) to ceil(ne/8)*8 (E~19.7): kills ~60% of the dead
// zero-coefficient FMA/gather work. Dead slots contribute exact +0.0f, so
// sums are BIT-IDENTICAL to R10 (absmax stays 0.75).
__global__ __launch_bounds__(256)
void k_agg(const short* __restrict__ q8, const float* __restrict__ qs,
           const unsigned* __restrict__ ell,
           const unsigned* __restrict__ degD,
           const float* __restrict__ comp,
           __hip_bfloat16* __restrict__ A,
           int r0, int rows)
{
    __shared__ float compS[NRELS * NBASES];
    __shared__ __align__(16) float cS[8][MAXDEG][8];   // 12 KB
    __shared__ unsigned sS[8][MAXDEG];                 // 1.5 KB
    __shared__ unsigned histS[8][NRELS];               // 512 B
    if (threadIdx.x < NRELS * NBASES) compS[threadIdx.x] = comp[threadIdx.x];
    __syncthreads();

    int wave = threadIdx.x >> 6, lane = threadIdx.x & 63;
    int half = lane >> 5, hl = lane & 31;
    int node = wave * 2 + half;
    int rl = blockIdx.x * 8 + node;
    bool alive = (rl < rows);
    int v = alive ? (r0 + rl) : 0;
    int ne = alive ? (int)degD[v] : 0; if (ne > MAXDEG) ne = MAXDEG;

    if (alive) {
        const unsigned* erow = ell + (size_t)v * MAXDEG;
        unsigned p0 = (hl < ne) ? erow[hl] : 0u;
        unsigned p1 = (hl + 32 < ne) ? erow[hl + 32] : 0u;
        if (hl < NRELS) histS[node][hl] = 0u;
        if (hl < ne)      atomicAdd(&histS[node][p0 & 15u], 1u);
        if (hl + 32 < ne) atomicAdd(&histS[node][p1 & 15u], 1u);
#pragma unroll
        for (int r = 0; r < 2; r++) {
            unsigned p = r ? p1 : p0;
            int slot = hl + 32 * r;
            if (slot >= MAXDEG) continue;              // MAXDEG=48: r=1 only hl<16
            bool val = (slot < ne);
            unsigned t = p & 15u;
            int s = val ? (int)(p >> 4) : 0;
            unsigned cnt = val ? histS[node][t] : 1u;
            if (cnt < 1u) cnt = 1u;
            float w = val ? (qs[s] / (float)cnt) : 0.f;
            f32x4v c0, c1;
#pragma unroll
            for (int b = 0; b < 4; b++) c0[b] = compS[t * NBASES + b] * w;
#pragma unroll
            for (int b = 0; b < 4; b++) c1[b] = compS[t * NBASES + 4 + b] * w;
            *(f32x4v*)&cS[node][slot][0] = c0;
            *(f32x4v*)&cS[node][slot][4] = c1;
            sS[node][slot] = (unsigned)s;
        }
    }

    f32x2v accA[NBASES], accB[NBASES];
#pragma unroll
    for (int b = 0; b < NBASES; b++) { accA[b] = (f32x2v){0.f,0.f}; accB[b] = (f32x2v){0.f,0.f}; }

    if (alive) {
        auto fma_edge = [&](unsigned d, const f32x4v& ca, const f32x4v& cb) {
            f32x2v f01, f23;
            f01.x = (float)(char)(d & 0xff);
            f01.y = (float)(char)((d >> 8) & 0xff);
            f23.x = (float)(char)((d >> 16) & 0xff);
            f23.y = (float)(char)(d >> 24);
            accA[0] += ca[0] * f01;  accB[0] += ca[0] * f23;
            accA[1] += ca[1] * f01;  accB[1] += ca[1] * f23;
            accA[2] += ca[2] * f01;  accB[2] += ca[2] * f23;
            accA[3] += ca[3] * f01;  accB[3] += ca[3] * f23;
            accA[4] += cb[0] * f01;  accB[4] += cb[0] * f23;
            accA[5] += cb[1] * f01;  accB[5] += cb[1] * f23;
            accA[6] += cb[2] * f01;  accB[6] += cb[2] * f23;
            accA[7] += cb[3] * f01;  accB[7] += cb[3] * f23;
        };
        auto batch16 = [&](int e0) {
            unsigned qd[16];
#pragma unroll
            for (int j = 0; j < 16; j++) {             // 16 gathers in flight
                unsigned s = sS[node][e0 + j];
                qd[j] = ((const unsigned*)(q8 + (size_t)s * 64))[hl];
            }
#pragma unroll
            for (int j = 0; j < 16; j++)
                fma_edge(qd[j], *(const f32x4v*)&cS[node][e0 + j][0],
                                *(const f32x4v*)&cS[node][e0 + j][4]);
        };
        auto batch8 = [&](int e0) {
            unsigned qd[8];
#pragma unroll
            for (int j = 0; j < 8; j++) {              // 8 gathers in flight
                unsigned s = sS[node][e0 + j];
                qd[j] = ((const unsigned*)(q8 + (size_t)s * 64))[hl];
            }
#pragma unroll
            for (int j = 0; j < 8; j++)
                fma_edge(qd[j], *(const f32x4v*)&cS[node][e0 + j][0],
                                *(const f32x4v*)&cS[node][e0 + j][4]);
        };
        int e0 = 0;
        for (; e0 + 16 <= ne; e0 += 16) batch16(e0);
        int rem = ne - e0;
        if (rem > 8)       batch16(e0);
        else if (rem > 0)  batch8(e0);

        __hip_bfloat16* Arow = A + (size_t)rl * KA;
#pragma unroll
        for (int b = 0; b < NBASES; b++) {             // 8 B coalesced plain store
            bf16x4s o;
            o.lo.x = __float2bfloat16(accA[b].x);
            o.lo.y = __float2bfloat16(accA[b].y);
            o.hi.x = __float2bfloat16(accB[b].x);
            o.hi.y = __float2bfloat16(accB[b].y);
            *(u16x4*)&Arow[b * 128 + 4 * hl] = *(const u16x4*)&o;
        }
    }
}

// ---- k_gemm: C[M,NT] = [A | hroot][M,1152] * WT[NT,1152]^T. 128x{128|64}
// tile, BK=32, 4 waves, mfma_f32_16x16x32_bf16, global_load_lds staging.
// Last 128 K cols stage directly from hin. RELU layers fuse per-row int8
// quant of the output. (R10 known-good.)
template<int NT, bool RELU, bool FINAL>
__global__ __launch_bounds__(256)
void k_gemm(const __hip_bfloat16* __restrict__ A,
            const __hip_bfloat16* __restrict__ hroot,
            const __hip_bfloat16* __restrict__ WT,
            const float* __restrict__ bias,
            void* __restrict__ outp,
            short* __restrict__ q8o, float* __restrict__ qso,
            int r0, int rows, int dout)
{
    constexpr int WM = (NT == 128) ? 2 : 4;
    constexpr int WN = 4 / WM;
    constexpr int MT = 128 / (16 * WM);
    constexpr int NTW = NT / (16 * WN);
    __shared__ __align__(16) __hip_bfloat16 As[128 * 32];
    __shared__ __align__(16) __hip_bfloat16 Bs[NT * 32];
    __shared__ unsigned rmax[128];
    int tid = threadIdx.x;
    int wave = tid >> 6, lane = tid & 63;
    int wm = wave % WM, wn = wave / WM;
    int bm = blockIdx.x * 128;
    int lm = lane & 15, lq = lane >> 4;
    if (RELU && tid < 128) rmax[tid] = 0u;
    f32x4v zero = {0.f, 0.f, 0.f, 0.f};
    f32x4v acc[MT][NTW];
#pragma unroll
    for (int a = 0; a < MT; a++)
#pragma unroll
        for (int b = 0; b < NTW; b++) acc[a][b] = zero;

    for (int k0 = 0; k0 < KTOT; k0 += 32) {
#pragma unroll
        for (int j = 0; j < 2; j++) {
            int slot = tid + 256 * j;
            int row = slot >> 2, kc = (slot & 3) << 3;
            const __hip_bfloat16* src;
            if (k0 < KA) {
                src = &A[(size_t)(bm + row) * KA + k0 + kc];
            } else {
                int gr = r0 + bm + row; if (gr > NNODES - 1) gr = NNODES - 1;
                src = &hroot[(size_t)gr * DFEAT + (k0 - KA) + kc];
            }
            __builtin_amdgcn_global_load_lds(
                (const __attribute__((address_space(1))) void*)src,
                (__attribute__((address_space(3))) void*)&As[slot * 8],
                16, 0, 0);
        }
#pragma unroll
        for (int j = 0; j < NT / 64; j++) {
            int slot = tid + 256 * j;
            int row = slot >> 2, kc = (slot & 3) << 3;
            __builtin_amdgcn_global_load_lds(
                (const __attribute__((address_space(1))) void*)
                    &WT[(size_t)row * KTOT + k0 + kc],
                (__attribute__((address_space(3))) void*)&Bs[slot * 8],
                16, 0, 0);
        }
        __syncthreads();
        bf16x8v af[MT], bfr[NTW];
#pragma unroll
        for (int mt = 0; mt < MT; mt++)
            af[mt] = *(const bf16x8v*)&As[(wm * (16 * MT) + mt * 16 + lm) * 32 + lq * 8];
#pragma unroll
        for (int nt = 0; nt < NTW; nt++)
            bfr[nt] = *(const bf16x8v*)&Bs[(wn * (16 * NTW) + nt * 16 + lm) * 32 + lq * 8];
#pragma unroll
        for (int mt = 0; mt < MT; mt++)
#pragma unroll
            for (int nt = 0; nt < NTW; nt++)
                acc[mt][nt] = __builtin_amdgcn_mfma_f32_16x16x32_bf16(
                    af[mt], bfr[nt], acc[mt][nt], 0, 0, 0);
        __syncthreads();
    }

    // pass 1: bias (+relu) in place, per-row absmax into LDS
#pragma unroll
    for (int mt = 0; mt < MT; mt++) {
#pragma unroll
        for (int i = 0; i < 4; i++) {
            float mx = 0.f;
#pragma unroll
            for (int nt = 0; nt < NTW; nt++) {
                int col = wn * (16 * NTW) + nt * 16 + lm;
                float bval = (!FINAL || col < dout) ? bias[col] : 0.f;
                float v = acc[mt][nt][i] + bval;
                if (RELU) { v = fmaxf(v, 0.f); mx = fmaxf(mx, v); }
                acc[mt][nt][i] = v;
            }
            if (RELU) {
                int lrow = wm * (16 * MT) + mt * 16 + lq * 4 + i;
                atomicMax(&rmax[lrow], __float_as_uint(mx));   // v>=0: uint order ok
            }
        }
    }
    if (RELU) __syncthreads();
    // pass 2: stores (+ fused quant for relu layers)
#pragma unroll
    for (int mt = 0; mt < MT; mt++) {
        int rbase = bm + wm * (16 * MT) + mt * 16 + lq * 4;
#pragma unroll
        for (int i = 0; i < 4; i++) {
            int rl = rbase + i;
            if (rl >= rows) continue;
            float inv = 0.f;
            if (RELU) {
                float m = __uint_as_float(rmax[wm * (16 * MT) + mt * 16 + lq * 4 + i]);
                inv = (m > 0.f) ? 127.f / m : 0.f;
            }
#pragma unroll
            for (int nt = 0; nt < NTW; nt++) {
                int col = wn * (16 * NTW) + nt * 16 + lm;
                float v = acc[mt][nt][i];
                if (FINAL) {
                    if (col < dout)
                        ((float*)outp)[(size_t)(r0 + rl) * NCLS + col] = v;
                } else {
                    ((__hip_bfloat16*)outp)[(size_t)(r0 + rl) * DFEAT + col] =
                        __float2bfloat16(v);
                    int qv = (int)rintf(v * inv);
                    ((char*)q8o)[(size_t)(r0 + rl) * DFEAT + col] = (char)qv;
                }
            }
        }
    }
    if (RELU) {
        if (tid < 128 && bm + tid < rows)
            qso[r0 + bm + tid] = __uint_as_float(rmax[tid]) * (1.f / 127.f);
    }
}

extern "C" void kernel_launch(void* const* d_in, const int* in_sizes, int n_in,
                              void* d_out, int out_size, void* d_ws, size_t ws_size,
                              hipStream_t stream)
{
    const float* x  = (const float*)d_in[0];
    const int* esrc = (const int*)d_in[1];
    const int* edst = (const int*)d_in[2];
    const int* etyp = (const int*)d_in[3];
    const float* basesA[3] = {(const float*)d_in[4], (const float*)d_in[8], (const float*)d_in[12]};
    const float* compA[3]  = {(const float*)d_in[5], (const float*)d_in[9], (const float*)d_in[13]};
    const float* rootA[3]  = {(const float*)d_in[6], (const float*)d_in[10], (const float*)d_in[14]};
    const float* biasA[3]  = {(const float*)d_in[7], (const float*)d_in[11], (const float*)d_in[15]};

    size_t off = 0;
    char* base = (char*)d_ws;
    auto carve = [&](size_t bytes) -> void* {
        void* r = base + off;
        off += (bytes + 255) & ~(size_t)255;
        return r;
    };
    __hip_bfloat16* xb = (__hip_bfloat16*)carve((size_t)NNODES * DFEAT * 2);
    __hip_bfloat16* h1 = (__hip_bfloat16*)carve((size_t)NNODES * DFEAT * 2);
    __hip_bfloat16* WT3 = (__hip_bfloat16*)carve((size_t)320 * KTOT * 2);
    unsigned* ell  = (unsigned*)carve((size_t)NPAD * MAXDEG * 4);
    unsigned* degD = (unsigned*)carve((size_t)NPAD * 4);
    short* q8A = (short*)carve((size_t)NNODES * 64 * 2);
    short* q8B = (short*)carve((size_t)NNODES * 64 * 2);
    float* qsA = (float*)carve((size_t)NNODES * 4);
    float* qsB = (float*)carve((size_t)NNODES * 4);
    unsigned* binCnt = (unsigned*)carve((size_t)NBUCK * 4);

    if (ws_size <= off) return;
    size_t arem = ws_size - off;
    if (arem < (size_t)NBUCK * BCAP * 8) return;
    __hip_bfloat16* Ab = (__hip_bfloat16*)(base + off);
    u64* bins = (u64*)Ab;                       // bins dead before first k_agg
    size_t arows = arem / ((size_t)KA * 2);
    if (arows > 100096) arows = 100096;
    int chunk = (int)(arows & ~(size_t)127);
    if (chunk < 128) return;

    hipMemsetAsync(binCnt, 0, (size_t)NBUCK * 4, stream);
    k_bin<<<BINBLKS + W3BLKS, 256, 0, stream>>>(
        x, xb, q8A, qsA, esrc, edst, etyp, binCnt, bins,
        basesA[0], rootA[0], basesA[1], rootA[1], basesA[2], rootA[2], WT3);
    k_ell<<<NBUCK, 256, 0, stream>>>(bins, binCnt, ell, degD);

    const __hip_bfloat16* hin = xb;
    __hip_bfloat16* houts[2] = {h1, xb};       // xb dead as root source after layer 0
    const short* q8in = q8A;  short* q8out = q8B;
    const float* qsin = qsA;  float* qsout = qsB;
    for (int l = 0; l < 3; l++) {
        int dout = (l == 2) ? NCLS : DFEAT;
        const __hip_bfloat16* WT = WT3 + (size_t)(l * 128) * KTOT;
        for (int r0 = 0; r0 < NNODES; r0 += chunk) {
            int rows = NNODES - r0; if (rows > chunk) rows = chunk;
            k_agg<<<(rows + 7) / 8, 256, 0, stream>>>(
                q8in, qsin, ell, degD, compA[l], Ab, r0, rows);
            int gm = (rows + 127) / 128;
            if (l < 2)
                k_gemm<128, true, false><<<gm, 256, 0, stream>>>(
                    Ab, hin, WT, biasA[l], houts[l], q8out, qsout, r0, rows, dout);
            else
                k_gemm<64, false, true><<<gm, 256, 0, stream>>>(
                    Ab, hin, WT, biasA[l], d_out, nullptr, nullptr, r0, rows, dout);
        }
        if (l < 2) {
            hin = houts[l];
            const short* tq = q8in; q8in = q8out; q8out = (short*)tq;
            const float* tf = qsin; qsin = qsout; qsout = (float*)tf;
        }
    }
}

// Round 14
// 634.077 us; speedup vs baseline: 1.1022x; 1.1022x over previous
//
#include <hip/hip_runtime.h>
#include <hip/hip_bf16.h>

#define NNODES 100000
#define NEDGES 1600000
#define NRELS 16
#define NBASES 8
#define DFEAT 128
#define NCLS 40
#define MAXDEG 48
#define KTOT 1152   // WT K extent: NBASES*128 + 128 (root)
#define KA   1024   // A K extent: NBASES*128 (root staged from hin)
#define NBUCK 196   // ceil(100000/512) destination buckets
#define NPAD  (NBUCK * 512)
#define BCAP  9216
#define BINBLKS 28125
#define W3BLKS  1440   // 320*1152/256

typedef __attribute__((ext_vector_type(8))) short bf16x8v;
typedef __attribute__((ext_vector_type(4))) float f32x4v;
typedef __attribute__((ext_vector_type(2))) float f32x2v;
typedef __attribute__((ext_vector_type(4))) unsigned short u16x4;
typedef unsigned long long u64;

struct __align__(8) bf16x4s { __hip_bfloat162 lo, hi; };

// ---- k_bin: cvq + edge binning + merged weight prep (R10 known-good) ----
__global__ __launch_bounds__(256)
void k_bin(const float* __restrict__ x, __hip_bfloat16* __restrict__ xb,
           short* __restrict__ q8, float* __restrict__ qs,
           const int* __restrict__ esrc, const int* __restrict__ edst,
           const int* __restrict__ etyp,
           unsigned* __restrict__ binCnt, u64* __restrict__ bins,
           const float* __restrict__ wb0, const float* __restrict__ wr0,
           const float* __restrict__ wb1, const float* __restrict__ wr1,
           const float* __restrict__ wb2, const float* __restrict__ wr2,
           __hip_bfloat16* __restrict__ WT3)
{
    unsigned bid = blockIdx.x;
    if (bid >= (unsigned)BINBLKS) {             // w3 block
        int idx = (int)(bid - BINBLKS) * 256 + threadIdx.x;
        int r = idx / KTOT, k = idx - r * KTOT;
        const float* bs; const float* rt; int o; int dout;
        if (r < 128)      { bs = wb0; rt = wr0; o = r;       dout = 128; }
        else if (r < 256) { bs = wb1; rt = wr1; o = r - 128; dout = 128; }
        else              { bs = wb2; rt = wr2; o = r - 256; dout = NCLS; }
        float v = 0.f;
        if (o < dout) v = (k < KA) ? bs[(size_t)k * dout + o]
                                   : rt[(size_t)(k - KA) * dout + o];
        WT3[idx] = __float2bfloat16(v);
        return;
    }
    if (bid % 9u == 0u) {                       // bin block: 512 edges
        __shared__ unsigned histS[NBUCK], rankS[NBUCK];
        __shared__ unsigned baseLS[NBUCK], baseGS[NBUCK];
        __shared__ unsigned wsumS[4];
        __shared__ u64 recS[512];
        int k = (int)(bid / 9u);
        int t = threadIdx.x, lane = t & 63, wv = t >> 6;
        for (int i = t; i < NBUCK; i += 256) { histS[i] = 0u; rankS[i] = 0u; }
        __syncthreads();
        int2 s2 = ((const int2*)esrc)[k * 256 + t];
        int2 d2 = ((const int2*)edst)[k * 256 + t];
        int2 t2 = ((const int2*)etyp)[k * 256 + t];
        unsigned b0 = (unsigned)d2.x >> 9, b1 = (unsigned)d2.y >> 9;
        u64 r0 = ((u64)(unsigned)d2.x << 21) | ((unsigned)s2.x << 4) | (unsigned)t2.x;
        u64 r1 = ((u64)(unsigned)d2.y << 21) | ((unsigned)s2.y << 4) | (unsigned)t2.y;
        atomicAdd(&histS[b0], 1u);
        atomicAdd(&histS[b1], 1u);
        __syncthreads();
        unsigned h = (t < NBUCK) ? histS[t] : 0u, v = h;
#pragma unroll
        for (int o = 1; o < 64; o <<= 1) {      // inclusive wave scan
            unsigned u = __shfl_up(v, o);
            if (lane >= o) v += u;
        }
        if (lane == 63) wsumS[wv] = v;
        __syncthreads();
        unsigned wo = 0;
        for (int w = 0; w < wv; w++) wo += wsumS[w];
        v += wo;
        if (t < NBUCK) {
            baseLS[t] = v - h;                  // exclusive local base
            baseGS[t] = atomicAdd(&binCnt[t], h);
        }
        __syncthreads();
        unsigned q0 = atomicAdd(&rankS[b0], 1u);
        recS[baseLS[b0] + q0] = r0;
        unsigned q1 = atomicAdd(&rankS[b1], 1u);
        recS[baseLS[b1] + q1] = r1;
        __syncthreads();
#pragma unroll
        for (int j = 0; j < 2; j++) {           // coalesced run writeout
            int idx = t + 256 * j;
            u64 rr = recS[idx];
            unsigned bb = (unsigned)(rr >> 21) >> 9;
            unsigned go = baseGS[bb] + ((unsigned)idx - baseLS[bb]);
            if (go < BCAP) bins[(size_t)bb * BCAP + go] = rr;
        }
    } else {                                    // cvq block: 4 nodes
        int cb = (int)(bid - bid / 9u - 1u);
        int wave = threadIdx.x >> 6, lane = threadIdx.x & 63;
        int v = cb * 4 + wave;
        if (v >= NNODES) return;
        float2 xv = ((const float2*)x)[(size_t)v * 64 + lane];
        __hip_bfloat162 bv;
        bv.x = __float2bfloat16(xv.x);
        bv.y = __float2bfloat16(xv.y);
        ((__hip_bfloat162*)xb)[(size_t)v * 64 + lane] = bv;
        float m = fmaxf(fabsf(xv.x), fabsf(xv.y));
#pragma unroll
        for (int o = 32; o; o >>= 1) m = fmaxf(m, __shfl_xor(m, o));
        float inv = (m > 0.f) ? 127.f / m : 0.f;
        int qx = (int)rintf(xv.x * inv), qy = (int)rintf(xv.y * inv);
        q8[(size_t)v * 64 + lane] = (short)((qx & 0xff) | (qy << 8));
        if (lane == 0) qs[v] = m * (1.f / 127.f);
    }
}

// ---- k_ell: bucket -> ELL window (MAXDEG=48) in LDS (R10 known-good) ----
__global__ __launch_bounds__(256)
void k_ell(const u64* __restrict__ bins, const unsigned* __restrict__ binCnt,
           unsigned* __restrict__ ell, unsigned* __restrict__ degD)
{
    __shared__ unsigned cntS[512];
    __shared__ unsigned ellS[512 * MAXDEG];     // 96 KB
    int b = blockIdx.x, t = threadIdx.x;
    for (int i = t; i < 512; i += 256) cntS[i] = 0u;
    __syncthreads();
    unsigned n = binCnt[b]; if (n > BCAP) n = BCAP;
    const u64* rp = bins + (size_t)b * BCAP;
    for (unsigned i = t; i < n; i += 256) {
        u64 r = rp[i];
        unsigned ld = ((unsigned)(r >> 21)) & 511u;
        unsigned slot = atomicAdd(&cntS[ld], 1u);
        if (slot < MAXDEG) ellS[ld * MAXDEG + slot] = (unsigned)(r & 0x1FFFFFu);
    }
    __syncthreads();
    size_t row0 = (size_t)b << 9;
    uint4* eo = (uint4*)(ell + row0 * MAXDEG);
    const uint4* ei = (const uint4*)ellS;
    for (int i = t; i < 512 * (MAXDEG / 4); i += 256)
        eo[i] = ei[i];                           // fully coalesced
    if (t < 256) { degD[row0 + t] = cntS[t]; degD[row0 + 256 + t] = cntS[256 + t]; }
}

// ---- k_agg: TWO nodes/wave. Single UNIFORM 8-deep gather pipeline (one code
// path -> no R13 dual-path VGPR bloat; qd[8] cuts 8 regs vs R10's qd[16]).
// Slots processed: ceil(ne/8)*8 (E~19.7) vs R10's ceil(ne/16)*16 (E~22.8),
// -13.5% inner work. MLP: 8 in-flight/wave x ~13 waves/SIMD covers L2
// latency. Dead slots are exact +0.0f -> sums BIT-IDENTICAL (absmax 0.75).
__global__ __launch_bounds__(256)
void k_agg(const short* __restrict__ q8, const float* __restrict__ qs,
           const unsigned* __restrict__ ell,
           const unsigned* __restrict__ degD,
           const float* __restrict__ comp,
           __hip_bfloat16* __restrict__ A,
           int r0, int rows)
{
    __shared__ float compS[NRELS * NBASES];
    __shared__ __align__(16) float cS[8][MAXDEG][8];   // 12 KB
    __shared__ unsigned sS[8][MAXDEG];                 // 1.5 KB
    __shared__ unsigned histS[8][NRELS];               // 512 B
    if (threadIdx.x < NRELS * NBASES) compS[threadIdx.x] = comp[threadIdx.x];
    __syncthreads();

    int wave = threadIdx.x >> 6, lane = threadIdx.x & 63;
    int half = lane >> 5, hl = lane & 31;
    int node = wave * 2 + half;
    int rl = blockIdx.x * 8 + node;
    bool alive = (rl < rows);
    int v = alive ? (r0 + rl) : 0;
    int ne = alive ? (int)degD[v] : 0; if (ne > MAXDEG) ne = MAXDEG;

    if (alive) {
        const unsigned* erow = ell + (size_t)v * MAXDEG;
        unsigned p0 = (hl < ne) ? erow[hl] : 0u;
        unsigned p1 = (hl + 32 < ne) ? erow[hl + 32] : 0u;
        if (hl < NRELS) histS[node][hl] = 0u;
        if (hl < ne)      atomicAdd(&histS[node][p0 & 15u], 1u);
        if (hl + 32 < ne) atomicAdd(&histS[node][p1 & 15u], 1u);
#pragma unroll
        for (int r = 0; r < 2; r++) {
            unsigned p = r ? p1 : p0;
            int slot = hl + 32 * r;
            if (slot >= MAXDEG) continue;              // MAXDEG=48: r=1 only hl<16
            bool val = (slot < ne);
            unsigned t = p & 15u;
            int s = val ? (int)(p >> 4) : 0;
            unsigned cnt = val ? histS[node][t] : 1u;
            if (cnt < 1u) cnt = 1u;
            float w = val ? (qs[s] / (float)cnt) : 0.f;
            f32x4v c0, c1;
#pragma unroll
            for (int b = 0; b < 4; b++) c0[b] = compS[t * NBASES + b] * w;
#pragma unroll
            for (int b = 0; b < 4; b++) c1[b] = compS[t * NBASES + 4 + b] * w;
            *(f32x4v*)&cS[node][slot][0] = c0;
            *(f32x4v*)&cS[node][slot][4] = c1;
            sS[node][slot] = (unsigned)s;
        }
    }

    f32x2v accA[NBASES], accB[NBASES];
#pragma unroll
    for (int b = 0; b < NBASES; b++) { accA[b] = (f32x2v){0.f,0.f}; accB[b] = (f32x2v){0.f,0.f}; }

    if (alive) {
        for (int e0 = 0; e0 < ne; e0 += 8) {
            unsigned qd[8];
#pragma unroll
            for (int j = 0; j < 8; j++) {              // 8 gathers in flight
                unsigned s = sS[node][e0 + j];
                qd[j] = ((const unsigned*)(q8 + (size_t)s * 64))[hl];
            }
#pragma unroll
            for (int j = 0; j < 8; j++) {
                f32x4v ca = *(const f32x4v*)&cS[node][e0 + j][0];
                f32x4v cb = *(const f32x4v*)&cS[node][e0 + j][4];
                unsigned d = qd[j];
                f32x2v f01, f23;
                f01.x = (float)(char)(d & 0xff);
                f01.y = (float)(char)((d >> 8) & 0xff);
                f23.x = (float)(char)((d >> 16) & 0xff);
                f23.y = (float)(char)(d >> 24);
                accA[0] += ca[0] * f01;  accB[0] += ca[0] * f23;
                accA[1] += ca[1] * f01;  accB[1] += ca[1] * f23;
                accA[2] += ca[2] * f01;  accB[2] += ca[2] * f23;
                accA[3] += ca[3] * f01;  accB[3] += ca[3] * f23;
                accA[4] += cb[0] * f01;  accB[4] += cb[0] * f23;
                accA[5] += cb[1] * f01;  accB[5] += cb[1] * f23;
                accA[6] += cb[2] * f01;  accB[6] += cb[2] * f23;
                accA[7] += cb[3] * f01;  accB[7] += cb[3] * f23;
            }
        }
        __hip_bfloat16* Arow = A + (size_t)rl * KA;
#pragma unroll
        for (int b = 0; b < NBASES; b++) {             // 8 B coalesced plain store
            bf16x4s o;
            o.lo.x = __float2bfloat16(accA[b].x);
            o.lo.y = __float2bfloat16(accA[b].y);
            o.hi.x = __float2bfloat16(accB[b].x);
            o.hi.y = __float2bfloat16(accB[b].y);
            *(u16x4*)&Arow[b * 128 + 4 * hl] = *(const u16x4*)&o;
        }
    }
}

// ---- k_gemm: C[M,NT] = [A | hroot][M,1152] * WT[NT,1152]^T. 128x{128|64}
// tile, BK=32, 4 waves, mfma_f32_16x16x32_bf16, global_load_lds staging.
// Last 128 K cols stage directly from hin. RELU layers fuse per-row int8
// quant of the output. (R10 known-good.)
template<int NT, bool RELU, bool FINAL>
__global__ __launch_bounds__(256)
void k_gemm(const __hip_bfloat16* __restrict__ A,
            const __hip_bfloat16* __restrict__ hroot,
            const __hip_bfloat16* __restrict__ WT,
            const float* __restrict__ bias,
            void* __restrict__ outp,
            short* __restrict__ q8o, float* __restrict__ qso,
            int r0, int rows, int dout)
{
    constexpr int WM = (NT == 128) ? 2 : 4;
    constexpr int WN = 4 / WM;
    constexpr int MT = 128 / (16 * WM);
    constexpr int NTW = NT / (16 * WN);
    __shared__ __align__(16) __hip_bfloat16 As[128 * 32];
    __shared__ __align__(16) __hip_bfloat16 Bs[NT * 32];
    __shared__ unsigned rmax[128];
    int tid = threadIdx.x;
    int wave = tid >> 6, lane = tid & 63;
    int wm = wave % WM, wn = wave / WM;
    int bm = blockIdx.x * 128;
    int lm = lane & 15, lq = lane >> 4;
    if (RELU && tid < 128) rmax[tid] = 0u;
    f32x4v zero = {0.f, 0.f, 0.f, 0.f};
    f32x4v acc[MT][NTW];
#pragma unroll
    for (int a = 0; a < MT; a++)
#pragma unroll
        for (int b = 0; b < NTW; b++) acc[a][b] = zero;

    for (int k0 = 0; k0 < KTOT; k0 += 32) {
#pragma unroll
        for (int j = 0; j < 2; j++) {
            int slot = tid + 256 * j;
            int row = slot >> 2, kc = (slot & 3) << 3;
            const __hip_bfloat16* src;
            if (k0 < KA) {
                src = &A[(size_t)(bm + row) * KA + k0 + kc];
            } else {
                int gr = r0 + bm + row; if (gr > NNODES - 1) gr = NNODES - 1;
                src = &hroot[(size_t)gr * DFEAT + (k0 - KA) + kc];
            }
            __builtin_amdgcn_global_load_lds(
                (const __attribute__((address_space(1))) void*)src,
                (__attribute__((address_space(3))) void*)&As[slot * 8],
                16, 0, 0);
        }
#pragma unroll
        for (int j = 0; j < NT / 64; j++) {
            int slot = tid + 256 * j;
            int row = slot >> 2, kc = (slot & 3) << 3;
            __builtin_amdgcn_global_load_lds(
                (const __attribute__((address_space(1))) void*)
                    &WT[(size_t)row * KTOT + k0 + kc],
                (__attribute__((address_space(3))) void*)&Bs[slot * 8],
                16, 0, 0);
        }
        __syncthreads();
        bf16x8v af[MT], bfr[NTW];
#pragma unroll
        for (int mt = 0; mt < MT; mt++)
            af[mt] = *(const bf16x8v*)&As[(wm * (16 * MT) + mt * 16 + lm) * 32 + lq * 8];
#pragma unroll
        for (int nt = 0; nt < NTW; nt++)
            bfr[nt] = *(const bf16x8v*)&Bs[(wn * (16 * NTW) + nt * 16 + lm) * 32 + lq * 8];
#pragma unroll
        for (int mt = 0; mt < MT; mt++)
#pragma unroll
            for (int nt = 0; nt < NTW; nt++)
                acc[mt][nt] = __builtin_amdgcn_mfma_f32_16x16x32_bf16(
                    af[mt], bfr[nt], acc[mt][nt], 0, 0, 0);
        __syncthreads();
    }

    // pass 1: bias (+relu) in place, per-row absmax into LDS
#pragma unroll
    for (int mt = 0; mt < MT; mt++) {
#pragma unroll
        for (int i = 0; i < 4; i++) {
            float mx = 0.f;
#pragma unroll
            for (int nt = 0; nt < NTW; nt++) {
                int col = wn * (16 * NTW) + nt * 16 + lm;
                float bval = (!FINAL || col < dout) ? bias[col] : 0.f;
                float v = acc[mt][nt][i] + bval;
                if (RELU) { v = fmaxf(v, 0.f); mx = fmaxf(mx, v); }
                acc[mt][nt][i] = v;
            }
            if (RELU) {
                int lrow = wm * (16 * MT) + mt * 16 + lq * 4 + i;
                atomicMax(&rmax[lrow], __float_as_uint(mx));   // v>=0: uint order ok
            }
        }
    }
    if (RELU) __syncthreads();
    // pass 2: stores (+ fused quant for relu layers)
#pragma unroll
    for (int mt = 0; mt < MT; mt++) {
        int rbase = bm + wm * (16 * MT) + mt * 16 + lq * 4;
#pragma unroll
        for (int i = 0; i < 4; i++) {
            int rl = rbase + i;
            if (rl >= rows) continue;
            float inv = 0.f;
            if (RELU) {
                float m = __uint_as_float(rmax[wm * (16 * MT) + mt * 16 + lq * 4 + i]);
                inv = (m > 0.f) ? 127.f / m : 0.f;
            }
#pragma unroll
            for (int nt = 0; nt < NTW; nt++) {
                int col = wn * (16 * NTW) + nt * 16 + lm;
                float v = acc[mt][nt][i];
                if (FINAL) {
                    if (col < dout)
                        ((float*)outp)[(size_t)(r0 + rl) * NCLS + col] = v;
                } else {
                    ((__hip_bfloat16*)outp)[(size_t)(r0 + rl) * DFEAT + col] =
                        __float2bfloat16(v);
                    int qv = (int)rintf(v * inv);
                    ((char*)q8o)[(size_t)(r0 + rl) * DFEAT + col] = (char)qv;
                }
            }
        }
    }
    if (RELU) {
        if (tid < 128 && bm + tid < rows)
            qso[r0 + bm + tid] = __uint_as_float(rmax[tid]) * (1.f / 127.f);
    }
}

extern "C" void kernel_launch(void* const* d_in, const int* in_sizes, int n_in,
                              void* d_out, int out_size, void* d_ws, size_t ws_size,
                              hipStream_t stream)
{
    const float* x  = (const float*)d_in[0];
    const int* esrc = (const int*)d_in[1];
    const int* edst = (const int*)d_in[2];
    const int* etyp = (const int*)d_in[3];
    const float* basesA[3] = {(const float*)d_in[4], (const float*)d_in[8], (const float*)d_in[12]};
    const float* compA[3]  = {(const float*)d_in[5], (const float*)d_in[9], (const float*)d_in[13]};
    const float* rootA[3]  = {(const float*)d_in[6], (const float*)d_in[10], (const float*)d_in[14]};
    const float* biasA[3]  = {(const float*)d_in[7], (const float*)d_in[11], (const float*)d_in[15]};

    size_t off = 0;
    char* base = (char*)d_ws;
    auto carve = [&](size_t bytes) -> void* {
        void* r = base + off;
        off += (bytes + 255) & ~(size_t)255;
        return r;
    };
    __hip_bfloat16* xb = (__hip_bfloat16*)carve((size_t)NNODES * DFEAT * 2);
    __hip_bfloat16* h1 = (__hip_bfloat16*)carve((size_t)NNODES * DFEAT * 2);
    __hip_bfloat16* WT3 = (__hip_bfloat16*)carve((size_t)320 * KTOT * 2);
    unsigned* ell  = (unsigned*)carve((size_t)NPAD * MAXDEG * 4);
    unsigned* degD = (unsigned*)carve((size_t)NPAD * 4);
    short* q8A = (short*)carve((size_t)NNODES * 64 * 2);
    short* q8B = (short*)carve((size_t)NNODES * 64 * 2);
    float* qsA = (float*)carve((size_t)NNODES * 4);
    float* qsB = (float*)carve((size_t)NNODES * 4);
    unsigned* binCnt = (unsigned*)carve((size_t)NBUCK * 4);

    if (ws_size <= off) return;
    size_t arem = ws_size - off;
    if (arem < (size_t)NBUCK * BCAP * 8) return;
    __hip_bfloat16* Ab = (__hip_bfloat16*)(base + off);
    u64* bins = (u64*)Ab;                       // bins dead before first k_agg
    size_t arows = arem / ((size_t)KA * 2);
    if (arows > 100096) arows = 100096;
    int chunk = (int)(arows & ~(size_t)127);
    if (chunk < 128) return;

    hipMemsetAsync(binCnt, 0, (size_t)NBUCK * 4, stream);
    k_bin<<<BINBLKS + W3BLKS, 256, 0, stream>>>(
        x, xb, q8A, qsA, esrc, edst, etyp, binCnt, bins,
        basesA[0], rootA[0], basesA[1], rootA[1], basesA[2], rootA[2], WT3);
    k_ell<<<NBUCK, 256, 0, stream>>>(bins, binCnt, ell, degD);

    const __hip_bfloat16* hin = xb;
    __hip_bfloat16* houts[2] = {h1, xb};       // xb dead as root source after layer 0
    const short* q8in = q8A;  short* q8out = q8B;
    const float* qsin = qsA;  float* qsout = qsB;
    for (int l = 0; l < 3; l++) {
        int dout = (l == 2) ? NCLS : DFEAT;
        const __hip_bfloat16* WT = WT3 + (size_t)(l * 128) * KTOT;
        for (int r0 = 0; r0 < NNODES; r0 += chunk) {
            int rows = NNODES - r0; if (rows > chunk) rows = chunk;
            k_agg<<<(rows + 7) / 8, 256, 0, stream>>>(
                q8in, qsin, ell, degD, compA[l], Ab, r0, rows);
            int gm = (rows + 127) / 128;
            if (l < 2)
                k_gemm<128, true, false><<<gm, 256, 0, stream>>>(
                    Ab, hin, WT, biasA[l], houts[l], q8out, qsout, r0, rows, dout);
            else
                k_gemm<64, false, true><<<gm, 256, 0, stream>>>(
                    Ab, hin, WT, biasA[l], d_out, nullptr, nullptr, r0, rows, dout);
        }
        if (l < 2) {
            hin = houts[l];
            const short* tq = q8in; q8in = q8out; q8out = (short*)tq;
            const float* tf = qsin; qsin = qsout; qsout = (float*)tf;
        }
    }
}